// Round 3
// baseline (4717.855 us; speedup 1.0000x reference)
//
#include <hip/hip_runtime.h>
#include <cstdint>
#include <cstddef>

// Problem: B=64, T=512, I=128, H=256, 4H=1024, C=3. All fp32 in/out.
typedef _Float16 half2_t __attribute__((ext_vector_type(2)));
typedef _Float16 half8_t __attribute__((ext_vector_type(8)));
typedef float f32x4 __attribute__((ext_vector_type(4)));

static __device__ __forceinline__ float fdot2(half2_t a, half2_t b, float c) {
    return __builtin_amdgcn_fdot2(a, b, c, false);
}
static __device__ __forceinline__ half2_t h2(unsigned int u) {
    return __builtin_bit_cast(half2_t, u);
}
static __device__ __forceinline__ float sigm(float x) {
    return 1.f / (1.f + __expf(-x));
}
static __device__ __forceinline__ float tanh_fast(float x) {
    float ax = fabsf(x);
    float e = __expf(2.f * ax);
    float r = 1.f - 2.f / (e + 1.f);
    return copysignf(r, x);
}

// ---------------------------------------------------------------------------
// prep: W_hh (1024x256 fp32) -> f16 k8-major: Wp[k8*1024 + row] = 8 halves of
// W[row][8*k8..]; bias = b_ih + b_hh
// ---------------------------------------------------------------------------
__global__ __launch_bounds__(256) void prep_whh(const float* __restrict__ Whh,
                                                const float* __restrict__ bih,
                                                const float* __restrict__ bhh,
                                                uint4* __restrict__ Wp,
                                                float* __restrict__ bias) {
    int n = blockIdx.x * 256 + threadIdx.x;  // 0..32767
    if (n < 1024) bias[n] = bih[n] + bhh[n];
    int row = n & 1023;
    int k8 = n >> 10;
    union { uint4 u; _Float16 h[8]; } cv;
#pragma unroll
    for (int j = 0; j < 8; ++j) cv.h[j] = (_Float16)Whh[row * 256 + k8 * 8 + j];
    Wp[k8 * 1024 + row] = cv.u;
}

// f32 -> f16, 4 elements/thread
__global__ __launch_bounds__(256) void cvt_f16(const float* __restrict__ in,
                                               _Float16* __restrict__ out, int n4) {
    int i = blockIdx.x * 256 + threadIdx.x;
    if (i < n4) {
        float4 v = ((const float4*)in)[i];
        union { ushort4 u; _Float16 h[4]; } cv;
        cv.h[0] = (_Float16)v.x; cv.h[1] = (_Float16)v.y;
        cv.h[2] = (_Float16)v.z; cv.h[3] = (_Float16)v.w;
        ((ushort4*)out)[i] = cv.u;
    }
}

// ---------------------------------------------------------------------------
// gemm_mfma: C[M][1024] = A[M][K](f16) * W[1024][K](f16)^T + bias, fp32 out.
// ---------------------------------------------------------------------------
__global__ __launch_bounds__(256) void gemm_mfma(const _Float16* __restrict__ A,
                                                 const _Float16* __restrict__ Bw,
                                                 const float* __restrict__ bias,
                                                 float* __restrict__ Cmat, int K) {
    __shared__ _Float16 As[64][72];
    __shared__ _Float16 Bs[64][72];
    const int tid = threadIdx.x;
    const int wave = tid >> 6, lane = tid & 63;
    const int quad = lane >> 4, l16 = lane & 15;
    const int m0 = blockIdx.x * 64, n0 = blockIdx.y * 64;
    const int sr = tid >> 2;
    const int sc = (tid & 3) * 16;

    f32x4 acc[4] = {};

    for (int k0 = 0; k0 < K; k0 += 64) {
        const uint4 a0v = *(const uint4*)(A + (size_t)(m0 + sr) * K + k0 + sc);
        const uint4 a1v = *(const uint4*)(A + (size_t)(m0 + sr) * K + k0 + sc + 8);
        const uint4 b0v = *(const uint4*)(Bw + (size_t)(n0 + sr) * K + k0 + sc);
        const uint4 b1v = *(const uint4*)(Bw + (size_t)(n0 + sr) * K + k0 + sc + 8);
        __syncthreads();
        *(uint4*)&As[sr][sc] = a0v;
        *(uint4*)&As[sr][sc + 8] = a1v;
        *(uint4*)&Bs[sr][sc] = b0v;
        *(uint4*)&Bs[sr][sc + 8] = b1v;
        __syncthreads();
#pragma unroll
        for (int kc = 0; kc < 64; kc += 32) {
            half8_t af = *(const half8_t*)&As[wave * 16 + l16][kc + quad * 8];
#pragma unroll
            for (int nb = 0; nb < 4; ++nb) {
                half8_t bf = *(const half8_t*)&Bs[nb * 16 + l16][kc + quad * 8];
                acc[nb] = __builtin_amdgcn_mfma_f32_16x16x32_f16(af, bf, acc[nb], 0, 0, 0);
            }
        }
    }
#pragma unroll
    for (int nb = 0; nb < 4; ++nb) {
#pragma unroll
        for (int i = 0; i < 4; ++i) {
            int row = m0 + wave * 16 + quad * 4 + i;
            int col = n0 + nb * 16 + l16;
            Cmat[(size_t)row * 1024 + col] = acc[nb][i] + bias[col];
        }
    }
}

// ---------------------------------------------------------------------------
// lstm_scan v3: 64 WGs x 512 thr (8 waves -> 2 waves/SIMD TLP).
// Thread tid owns gate rows tid and tid+512:
//   tid<256   -> i_j, g_j  (j=tid), keeps cell state c_j
//   tid>=256  -> f_j, o_j  (j=tid-256), computes sigm and exchanges via LDS
// Weights k<128 of both rows in 128 VGPRs (persistent); k>=128 streamed from
// L2 with a 4-deep rolling prefetch whose addresses repeat every step (the
// pipeline rolls across the step boundary -> no start-of-step stall).
// h kept f16 in LDS; history buffered in LDS, flushed every 16 steps
// (store_all=1) or only last step stored compact [b][256] (store_all=0).
// ---------------------------------------------------------------------------
__global__ __launch_bounds__(512, 2) void lstm_scan(const float* __restrict__ gx,
                                                    const uint4* __restrict__ Wp,
                                                    _Float16* __restrict__ h_out,
                                                    int store_all) {
    const int b = blockIdx.x;
    const int tid = threadIdx.x;   // 0..511
    const int j = tid & 255;
    const bool isIG = tid < 256;

    __shared__ _Float16 hsh[256] __attribute__((aligned(16)));
    __shared__ float exf[256];
    __shared__ float exo[256];
    __shared__ _Float16 hist[16][256] __attribute__((aligned(16)));

    // persistent register weights: k8 = 0..15 (k<128), rows tid and tid+512
    uint4 wl[16], wh[16];
#pragma unroll
    for (int u = 0; u < 16; ++u) {
        wl[u] = Wp[u * 1024 + tid];
        wh[u] = Wp[u * 1024 + 512 + tid];
    }
    const uint4* S = Wp + 16 * 1024;  // streamed chunks, k8 = 16..31

    // 4-deep rolling prefetch (addresses are t-invariant)
    uint4 pl[4], ph[4];
#pragma unroll
    for (int u = 0; u < 4; ++u) {
        pl[u] = S[u * 1024 + tid];
        ph[u] = S[u * 1024 + 512 + tid];
    }

    if (isIG) hsh[j] = (_Float16)0.f;
    float c = 0.f;
    const float* gxb = gx + (size_t)b * 512 * 1024;
    float gl = gxb[tid], gh = gxb[512 + tid];  // gx for t=0
    __syncthreads();

    for (int t = 0; t < 512; ++t) {
        // prefetch next step's gx (consumed next iteration; ~1 step of slack)
        float gl_n = 0.f, gh_n = 0.f;
        if (t < 511) {
            const float* g4 = gxb + (size_t)(t + 1) * 1024;
            gl_n = g4[tid];
            gh_n = g4[512 + tid];
        }

        const uint4* hb = (const uint4*)hsh;
        float a0 = 0.f, a1 = 0.f;

        // register half: k8 = 0..15
#pragma unroll
        for (int u = 0; u < 16; ++u) {
            const uint4 hv = hb[u];
            const half2_t h0 = h2(hv.x), h1 = h2(hv.y), hv2 = h2(hv.z), h3 = h2(hv.w);
            a0 = fdot2(h2(wl[u].x), h0, a0); a0 = fdot2(h2(wl[u].y), h1, a0);
            a0 = fdot2(h2(wl[u].z), hv2, a0); a0 = fdot2(h2(wl[u].w), h3, a0);
            a1 = fdot2(h2(wh[u].x), h0, a1); a1 = fdot2(h2(wh[u].y), h1, a1);
            a1 = fdot2(h2(wh[u].z), hv2, a1); a1 = fdot2(h2(wh[u].w), h3, a1);
        }
        // streamed half: k8 = 16..31, rolling prefetch wraps into next step
#pragma unroll
        for (int u = 0; u < 16; ++u) {
            const uint4 cl = pl[u & 3], ch = ph[u & 3];
            const int nu = (u + 4) & 15;
            pl[u & 3] = S[nu * 1024 + tid];
            ph[u & 3] = S[nu * 1024 + 512 + tid];
            const uint4 hv = hb[16 + u];
            const half2_t h0 = h2(hv.x), h1 = h2(hv.y), hv2 = h2(hv.z), h3 = h2(hv.w);
            a0 = fdot2(h2(cl.x), h0, a0); a0 = fdot2(h2(cl.y), h1, a0);
            a0 = fdot2(h2(cl.z), hv2, a0); a0 = fdot2(h2(cl.w), h3, a0);
            a1 = fdot2(h2(ch.x), h0, a1); a1 = fdot2(h2(ch.y), h1, a1);
            a1 = fdot2(h2(ch.z), hv2, a1); a1 = fdot2(h2(ch.w), h3, a1);
        }

        const float plo = a0 + gl;  // pre-activation, row tid
        const float phi = a1 + gh;  // pre-activation, row tid+512
        float v0, v1;
        if (isIG) {
            v0 = sigm(plo);        // i_j
            v1 = tanh_fast(phi);   // g_j
        } else {
            exf[j] = sigm(plo);    // f_j
            exo[j] = sigm(phi);    // o_j
        }
        gl = gl_n; gh = gh_n;
        __syncthreads();           // exchange visible (lgkm-only drain + gx/stream acks)
        if (isIG) {
            const float fv = exf[j], ov = exo[j];
            c = fv * c + v0 * v1;
            const _Float16 hh = (_Float16)(ov * tanh_fast(c));
            hsh[j] = hh;
            hist[t & 15][j] = hh;
        }
        __syncthreads();           // h visible before next step's reads
        if (store_all && (t & 15) == 15) {
            // flush 16 steps (8 KB) -> HBM; hist flat layout == h_out layout
            const uint4 v = ((const uint4*)hist)[tid];
            *(uint4*)(h_out + (size_t)b * 512 * 256 + (size_t)(t - 15) * 256 + tid * 8) = v;
        }
    }
    if (!store_all && isIG) {
        h_out[(size_t)b * 256 + j] = hsh[j];  // compact last-h for the FC
    }
}

// ---------------------------------------------------------------------------
// fc_softmax: logits = hlast[b,:](f16) @ fc_w^T + fc_b, softmax over 3
// ---------------------------------------------------------------------------
__global__ __launch_bounds__(64) void fc_softmax(const _Float16* __restrict__ hlast,
                                                 const float* __restrict__ fcw,
                                                 const float* __restrict__ fcb,
                                                 float* __restrict__ out) {
    const int b = blockIdx.x;
    const int lane = threadIdx.x;
    const _Float16* h = hlast + (size_t)b * 256;
    float p0 = 0.f, p1 = 0.f, p2 = 0.f;
    for (int k = lane; k < 256; k += 64) {
        float hv = (float)h[k];
        p0 += hv * fcw[k];
        p1 += hv * fcw[256 + k];
        p2 += hv * fcw[512 + k];
    }
#pragma unroll
    for (int off = 32; off > 0; off >>= 1) {
        p0 += __shfl_down(p0, off);
        p1 += __shfl_down(p1, off);
        p2 += __shfl_down(p2, off);
    }
    if (lane == 0) {
        float l0 = p0 + fcb[0], l1 = p1 + fcb[1], l2 = p2 + fcb[2];
        float m = fmaxf(l0, fmaxf(l1, l2));
        float e0 = __expf(l0 - m), e1 = __expf(l1 - m), e2 = __expf(l2 - m);
        float s = 1.f / (e0 + e1 + e2);
        out[b * 3 + 0] = e0 * s;
        out[b * 3 + 1] = e1 * s;
        out[b * 3 + 2] = e2 * s;
    }
}

extern "C" void kernel_launch(void* const* d_in, const int* in_sizes, int n_in,
                              void* d_out, int out_size, void* d_ws, size_t ws_size,
                              hipStream_t stream) {
    const float* x    = (const float*)d_in[0];
    const float* Wih0 = (const float*)d_in[1];
    const float* Whh0 = (const float*)d_in[2];
    const float* bih0 = (const float*)d_in[3];
    const float* bhh0 = (const float*)d_in[4];
    const float* Wih1 = (const float*)d_in[5];
    const float* Whh1 = (const float*)d_in[6];
    const float* bih1 = (const float*)d_in[7];
    const float* bhh1 = (const float*)d_in[8];
    const float* fcw  = (const float*)d_in[9];
    const float* fcb  = (const float*)d_in[10];
    float* out = (float*)d_out;

    // workspace layout (~161 MB)
    char* ws = (char*)d_ws;
    float* gx        = (float*)ws;     ws += (size_t)32768 * 1024 * 4;  // 134.2 MB
    _Float16* h0f    = (_Float16*)ws;  ws += (size_t)32768 * 256 * 2;   // 16.8 MB
    _Float16* xh     = (_Float16*)ws;  ws += (size_t)32768 * 128 * 2;   // 8.4 MB
    _Float16* hlast  = (_Float16*)ws;  ws += (size_t)64 * 256 * 2;      // 32 KB
    _Float16* Wih0h  = (_Float16*)ws;  ws += (size_t)1024 * 128 * 2;    // 256 KB
    _Float16* Wih1h  = (_Float16*)ws;  ws += (size_t)1024 * 256 * 2;    // 512 KB
    uint4* Wp0       = (uint4*)ws;     ws += (size_t)1024 * 256 * 2;    // 512 KB
    uint4* Wp1       = (uint4*)ws;     ws += (size_t)1024 * 256 * 2;    // 512 KB
    float* bias0     = (float*)ws;     ws += 4096;
    float* bias1     = (float*)ws;     ws += 4096;

    prep_whh<<<128, 256, 0, stream>>>(Whh0, bih0, bhh0, Wp0, bias0);
    prep_whh<<<128, 256, 0, stream>>>(Whh1, bih1, bhh1, Wp1, bias1);
    cvt_f16<<<4096, 256, 0, stream>>>(x, xh, 32768 * 128 / 4);
    cvt_f16<<<128, 256, 0, stream>>>(Wih0, Wih0h, 1024 * 128 / 4);
    cvt_f16<<<256, 256, 0, stream>>>(Wih1, Wih1h, 1024 * 256 / 4);

    // layer 0
    gemm_mfma<<<dim3(512, 16), 256, 0, stream>>>(xh, Wih0h, bias0, gx, 128);
    lstm_scan<<<64, 512, 0, stream>>>(gx, Wp0, h0f, 1);

    // layer 1
    gemm_mfma<<<dim3(512, 16), 256, 0, stream>>>(h0f, Wih1h, bias1, gx, 256);
    lstm_scan<<<64, 512, 0, stream>>>(gx, Wp1, hlast, 0);

    fc_softmax<<<64, 64, 0, stream>>>(hlast, fcw, fcb, out);
}

// Round 4
// 2261.301 us; speedup vs baseline: 2.0863x; 2.0863x over previous
//
#include <hip/hip_runtime.h>
#include <cstdint>
#include <cstddef>

// Problem: B=64, T=512, I=128, H=256, 4H=1024, C=3. All fp32 in/out.
typedef _Float16 half2_t __attribute__((ext_vector_type(2)));
typedef _Float16 half8_t __attribute__((ext_vector_type(8)));
typedef float f32x4 __attribute__((ext_vector_type(4)));

static __device__ __forceinline__ float fdot2(half2_t a, half2_t b, float c) {
    return __builtin_amdgcn_fdot2(a, b, c, false);
}
static __device__ __forceinline__ half2_t h2(unsigned int u) {
    return __builtin_bit_cast(half2_t, u);
}
static __device__ __forceinline__ float sigm(float x) {
    return 1.f / (1.f + __expf(-x));
}
static __device__ __forceinline__ float tanh_fast(float x) {
    float ax = fabsf(x);
    float e = __expf(2.f * ax);
    float r = 1.f - 2.f / (e + 1.f);
    return copysignf(r, x);
}

// ---------------------------------------------------------------------------
// prep: W_hh (1024x256 fp32) -> f16 k8-major: Wp[k8*1024 + row] = 8 halves of
// W[row][8*k8..]; bias = b_ih + b_hh
// ---------------------------------------------------------------------------
__global__ __launch_bounds__(256) void prep_whh(const float* __restrict__ Whh,
                                                const float* __restrict__ bih,
                                                const float* __restrict__ bhh,
                                                uint4* __restrict__ Wp,
                                                float* __restrict__ bias) {
    int n = blockIdx.x * 256 + threadIdx.x;  // 0..32767
    if (n < 1024) bias[n] = bih[n] + bhh[n];
    int row = n & 1023;
    int k8 = n >> 10;
    union { uint4 u; _Float16 h[8]; } cv;
#pragma unroll
    for (int j = 0; j < 8; ++j) cv.h[j] = (_Float16)Whh[row * 256 + k8 * 8 + j];
    Wp[k8 * 1024 + row] = cv.u;
}

// f32 -> f16, 4 elements/thread
__global__ __launch_bounds__(256) void cvt_f16(const float* __restrict__ in,
                                               _Float16* __restrict__ out, int n4) {
    int i = blockIdx.x * 256 + threadIdx.x;
    if (i < n4) {
        float4 v = ((const float4*)in)[i];
        union { ushort4 u; _Float16 h[4]; } cv;
        cv.h[0] = (_Float16)v.x; cv.h[1] = (_Float16)v.y;
        cv.h[2] = (_Float16)v.z; cv.h[3] = (_Float16)v.w;
        ((ushort4*)out)[i] = cv.u;
    }
}

// ---------------------------------------------------------------------------
// gemm_mfma: C[M][1024] = A[M][K](f16) * W[1024][K](f16)^T + bias, fp32 out.
// ---------------------------------------------------------------------------
__global__ __launch_bounds__(256) void gemm_mfma(const _Float16* __restrict__ A,
                                                 const _Float16* __restrict__ Bw,
                                                 const float* __restrict__ bias,
                                                 float* __restrict__ Cmat, int K) {
    __shared__ _Float16 As[64][72];
    __shared__ _Float16 Bs[64][72];
    const int tid = threadIdx.x;
    const int wave = tid >> 6, lane = tid & 63;
    const int quad = lane >> 4, l16 = lane & 15;
    const int m0 = blockIdx.x * 64, n0 = blockIdx.y * 64;
    const int sr = tid >> 2;
    const int sc = (tid & 3) * 16;

    f32x4 acc[4] = {};

    for (int k0 = 0; k0 < K; k0 += 64) {
        const uint4 a0v = *(const uint4*)(A + (size_t)(m0 + sr) * K + k0 + sc);
        const uint4 a1v = *(const uint4*)(A + (size_t)(m0 + sr) * K + k0 + sc + 8);
        const uint4 b0v = *(const uint4*)(Bw + (size_t)(n0 + sr) * K + k0 + sc);
        const uint4 b1v = *(const uint4*)(Bw + (size_t)(n0 + sr) * K + k0 + sc + 8);
        __syncthreads();
        *(uint4*)&As[sr][sc] = a0v;
        *(uint4*)&As[sr][sc + 8] = a1v;
        *(uint4*)&Bs[sr][sc] = b0v;
        *(uint4*)&Bs[sr][sc + 8] = b1v;
        __syncthreads();
#pragma unroll
        for (int kc = 0; kc < 64; kc += 32) {
            half8_t af = *(const half8_t*)&As[wave * 16 + l16][kc + quad * 8];
#pragma unroll
            for (int nb = 0; nb < 4; ++nb) {
                half8_t bf = *(const half8_t*)&Bs[nb * 16 + l16][kc + quad * 8];
                acc[nb] = __builtin_amdgcn_mfma_f32_16x16x32_f16(af, bf, acc[nb], 0, 0, 0);
            }
        }
    }
#pragma unroll
    for (int nb = 0; nb < 4; ++nb) {
#pragma unroll
        for (int i = 0; i < 4; ++i) {
            int row = m0 + wave * 16 + quad * 4 + i;
            int col = n0 + nb * 16 + l16;
            Cmat[(size_t)row * 1024 + col] = acc[nb][i] + bias[col];
        }
    }
}

// ---------------------------------------------------------------------------
// lstm_scan v4: 64 WGs x 512 thr (8 waves, 2 waves/SIMD). Thread tid owns
// gate rows tid and tid+512. Weight placement per thread-row-pair:
//   k8 = 0..15   : 128 VGPRs (persistent across all 512 steps)
//   k8 = 16..23  : 128 KB LDS (staged once at kernel start)
//   k8 = 24..31  : L2, loaded in full at step top (64 VGPR buffer, consumed
//                  ~600 cyc later -> latency covered, no cross-barrier state)
// __launch_bounds__(512,1): CUDA blocks-semantics -> 256-VGPR cap (R3's "2"
// produced a 128 cap and spilled everything).
// ---------------------------------------------------------------------------
__global__ __launch_bounds__(512, 1) void lstm_scan(const float* __restrict__ gx,
                                                    const uint4* __restrict__ Wp,
                                                    _Float16* __restrict__ h_out,
                                                    int store_all) {
    const int b = blockIdx.x;
    const int tid = threadIdx.x;   // 0..511
    const int j = tid & 255;
    const bool isIG = tid < 256;

    __shared__ uint4 wlds[8 * 1024];  // 128 KB: k8 = 16..23, [k8'][row]
    __shared__ _Float16 hsh[256] __attribute__((aligned(16)));
    __shared__ float exf[256];
    __shared__ float exo[256];
    __shared__ _Float16 hist[16][256] __attribute__((aligned(16)));

    // stage k8=16..23 into LDS (flat layout identical to Wp slice)
#pragma unroll
    for (int q = 0; q < 16; ++q) {
        int idx = q * 512 + tid;
        wlds[idx] = Wp[16 * 1024 + idx];
    }

    // persistent register weights: k8 = 0..15, rows tid and tid+512
    uint4 wl[16], wh[16];
#pragma unroll
    for (int u = 0; u < 16; ++u) {
        wl[u] = Wp[u * 1024 + tid];
        wh[u] = Wp[u * 1024 + 512 + tid];
    }
    const uint4* S = Wp + 24 * 1024;  // k8 = 24..31 streamed from L2

    if (isIG) hsh[j] = (_Float16)0.f;
    float c = 0.f;
    const float* gxb = gx + (size_t)b * 512 * 1024;
    float gl = gxb[tid], gh = gxb[512 + tid];  // gx for t=0
    __syncthreads();  // wlds + hsh visible

    for (int t = 0; t < 512; ++t) {
        // issue this step's L2 stream loads; consumed at k8=24..31
        uint4 sl[8], sh[8];
#pragma unroll
        for (int u = 0; u < 8; ++u) {
            sl[u] = S[u * 1024 + tid];
            sh[u] = S[u * 1024 + 512 + tid];
        }
        // prefetch next step's gx
        float gl_n = 0.f, gh_n = 0.f;
        if (t < 511) {
            const float* g4 = gxb + (size_t)(t + 1) * 1024;
            gl_n = g4[tid];
            gh_n = g4[512 + tid];
        }

        const uint4* hb = (const uint4*)hsh;
        float a0x = 0.f, a0y = 0.f, a1x = 0.f, a1y = 0.f;  // split dep chains

        // register half: k8 = 0..15
#pragma unroll
        for (int u = 0; u < 16; ++u) {
            const uint4 hv = hb[u];
            const half2_t h0 = h2(hv.x), h1 = h2(hv.y), hv2 = h2(hv.z), h3 = h2(hv.w);
            a0x = fdot2(h2(wl[u].x), h0, a0x); a0x = fdot2(h2(wl[u].y), h1, a0x);
            a0y = fdot2(h2(wl[u].z), hv2, a0y); a0y = fdot2(h2(wl[u].w), h3, a0y);
            a1x = fdot2(h2(wh[u].x), h0, a1x); a1x = fdot2(h2(wh[u].y), h1, a1x);
            a1y = fdot2(h2(wh[u].z), hv2, a1y); a1y = fdot2(h2(wh[u].w), h3, a1y);
        }
        // LDS half: k8 = 16..23
#pragma unroll
        for (int u = 0; u < 8; ++u) {
            const uint4 cl = wlds[u * 1024 + tid];
            const uint4 ch = wlds[u * 1024 + 512 + tid];
            const uint4 hv = hb[16 + u];
            const half2_t h0 = h2(hv.x), h1 = h2(hv.y), hv2 = h2(hv.z), h3 = h2(hv.w);
            a0x = fdot2(h2(cl.x), h0, a0x); a0x = fdot2(h2(cl.y), h1, a0x);
            a0y = fdot2(h2(cl.z), hv2, a0y); a0y = fdot2(h2(cl.w), h3, a0y);
            a1x = fdot2(h2(ch.x), h0, a1x); a1x = fdot2(h2(ch.y), h1, a1x);
            a1y = fdot2(h2(ch.z), hv2, a1y); a1y = fdot2(h2(ch.w), h3, a1y);
        }
        // streamed half: k8 = 24..31 (loads issued at step top)
#pragma unroll
        for (int u = 0; u < 8; ++u) {
            const uint4 cl = sl[u], ch = sh[u];
            const uint4 hv = hb[24 + u];
            const half2_t h0 = h2(hv.x), h1 = h2(hv.y), hv2 = h2(hv.z), h3 = h2(hv.w);
            a0x = fdot2(h2(cl.x), h0, a0x); a0x = fdot2(h2(cl.y), h1, a0x);
            a0y = fdot2(h2(cl.z), hv2, a0y); a0y = fdot2(h2(cl.w), h3, a0y);
            a1x = fdot2(h2(ch.x), h0, a1x); a1x = fdot2(h2(ch.y), h1, a1x);
            a1y = fdot2(h2(ch.z), hv2, a1y); a1y = fdot2(h2(ch.w), h3, a1y);
        }

        const float plo = a0x + a0y + gl;  // pre-activation, row tid
        const float phi = a1x + a1y + gh;  // pre-activation, row tid+512
        float v0 = 0.f, v1 = 0.f;
        if (isIG) {
            v0 = sigm(plo);        // i_j
            v1 = tanh_fast(phi);   // g_j
        } else {
            exf[j] = sigm(plo);    // f_j
            exo[j] = sigm(phi);    // o_j
        }
        gl = gl_n; gh = gh_n;
        __syncthreads();           // exchange visible; all hsh reads done
        if (isIG) {
            const float fv = exf[j], ov = exo[j];
            c = fv * c + v0 * v1;
            const _Float16 hh = (_Float16)(ov * tanh_fast(c));
            hsh[j] = hh;
            hist[t & 15][j] = hh;
        }
        __syncthreads();           // new h visible
        if (store_all && (t & 15) == 15) {
            const uint4 v = ((const uint4*)hist)[tid];
            *(uint4*)(h_out + (size_t)b * 512 * 256 + (size_t)(t - 15) * 256 + tid * 8) = v;
        }
    }
    if (!store_all && isIG) {
        h_out[(size_t)b * 256 + j] = hsh[j];  // compact last-h for the FC
    }
}

// ---------------------------------------------------------------------------
// fc_softmax: logits = hlast[b,:](f16) @ fc_w^T + fc_b, softmax over 3
// ---------------------------------------------------------------------------
__global__ __launch_bounds__(64) void fc_softmax(const _Float16* __restrict__ hlast,
                                                 const float* __restrict__ fcw,
                                                 const float* __restrict__ fcb,
                                                 float* __restrict__ out) {
    const int b = blockIdx.x;
    const int lane = threadIdx.x;
    const _Float16* h = hlast + (size_t)b * 256;
    float p0 = 0.f, p1 = 0.f, p2 = 0.f;
    for (int k = lane; k < 256; k += 64) {
        float hv = (float)h[k];
        p0 += hv * fcw[k];
        p1 += hv * fcw[256 + k];
        p2 += hv * fcw[512 + k];
    }
#pragma unroll
    for (int off = 32; off > 0; off >>= 1) {
        p0 += __shfl_down(p0, off);
        p1 += __shfl_down(p1, off);
        p2 += __shfl_down(p2, off);
    }
    if (lane == 0) {
        float l0 = p0 + fcb[0], l1 = p1 + fcb[1], l2 = p2 + fcb[2];
        float m = fmaxf(l0, fmaxf(l1, l2));
        float e0 = __expf(l0 - m), e1 = __expf(l1 - m), e2 = __expf(l2 - m);
        float s = 1.f / (e0 + e1 + e2);
        out[b * 3 + 0] = e0 * s;
        out[b * 3 + 1] = e1 * s;
        out[b * 3 + 2] = e2 * s;
    }
}

extern "C" void kernel_launch(void* const* d_in, const int* in_sizes, int n_in,
                              void* d_out, int out_size, void* d_ws, size_t ws_size,
                              hipStream_t stream) {
    const float* x    = (const float*)d_in[0];
    const float* Wih0 = (const float*)d_in[1];
    const float* Whh0 = (const float*)d_in[2];
    const float* bih0 = (const float*)d_in[3];
    const float* bhh0 = (const float*)d_in[4];
    const float* Wih1 = (const float*)d_in[5];
    const float* Whh1 = (const float*)d_in[6];
    const float* bih1 = (const float*)d_in[7];
    const float* bhh1 = (const float*)d_in[8];
    const float* fcw  = (const float*)d_in[9];
    const float* fcb  = (const float*)d_in[10];
    float* out = (float*)d_out;

    // workspace layout (~161 MB)
    char* ws = (char*)d_ws;
    float* gx        = (float*)ws;     ws += (size_t)32768 * 1024 * 4;  // 134.2 MB
    _Float16* h0f    = (_Float16*)ws;  ws += (size_t)32768 * 256 * 2;   // 16.8 MB
    _Float16* xh     = (_Float16*)ws;  ws += (size_t)32768 * 128 * 2;   // 8.4 MB
    _Float16* hlast  = (_Float16*)ws;  ws += (size_t)64 * 256 * 2;      // 32 KB
    _Float16* Wih0h  = (_Float16*)ws;  ws += (size_t)1024 * 128 * 2;    // 256 KB
    _Float16* Wih1h  = (_Float16*)ws;  ws += (size_t)1024 * 256 * 2;    // 512 KB
    uint4* Wp0       = (uint4*)ws;     ws += (size_t)1024 * 256 * 2;    // 512 KB
    uint4* Wp1       = (uint4*)ws;     ws += (size_t)1024 * 256 * 2;    // 512 KB
    float* bias0     = (float*)ws;     ws += 4096;
    float* bias1     = (float*)ws;     ws += 4096;

    prep_whh<<<128, 256, 0, stream>>>(Whh0, bih0, bhh0, Wp0, bias0);
    prep_whh<<<128, 256, 0, stream>>>(Whh1, bih1, bhh1, Wp1, bias1);
    cvt_f16<<<4096, 256, 0, stream>>>(x, xh, 32768 * 128 / 4);
    cvt_f16<<<128, 256, 0, stream>>>(Wih0, Wih0h, 1024 * 128 / 4);
    cvt_f16<<<256, 256, 0, stream>>>(Wih1, Wih1h, 1024 * 256 / 4);

    // layer 0
    gemm_mfma<<<dim3(512, 16), 256, 0, stream>>>(xh, Wih0h, bias0, gx, 128);
    lstm_scan<<<64, 512, 0, stream>>>(gx, Wp0, h0f, 1);

    // layer 1
    gemm_mfma<<<dim3(512, 16), 256, 0, stream>>>(h0f, Wih1h, bias1, gx, 256);
    lstm_scan<<<64, 512, 0, stream>>>(gx, Wp1, hlast, 0);

    fc_softmax<<<64, 64, 0, stream>>>(hlast, fcw, fcb, out);
}

// Round 5
// 2257.256 us; speedup vs baseline: 2.0901x; 1.0018x over previous
//
#include <hip/hip_runtime.h>
#include <cstdint>
#include <cstddef>

// Problem: B=64, T=512, I=128, H=256, 4H=1024, C=3. All fp32 in/out.
typedef _Float16 half2_t __attribute__((ext_vector_type(2)));
typedef _Float16 half8_t __attribute__((ext_vector_type(8)));
typedef float f32x4 __attribute__((ext_vector_type(4)));

static __device__ __forceinline__ float fdot2(half2_t a, half2_t b, float c) {
    return __builtin_amdgcn_fdot2(a, b, c, false);
}
static __device__ __forceinline__ half2_t h2(unsigned int u) {
    return __builtin_bit_cast(half2_t, u);
}
static __device__ __forceinline__ float sigm(float x) {
    return 1.f / (1.f + __expf(-x));
}
static __device__ __forceinline__ float tanh_fast(float x) {
    float ax = fabsf(x);
    float e = __expf(2.f * ax);
    float r = 1.f - 2.f / (e + 1.f);
    return copysignf(r, x);
}

// ---------------------------------------------------------------------------
// prep: W_hh (1024x256 fp32) -> f16 k8-major: Wp[k8*1024 + row] = 8 halves of
// W[row][8*k8..]; bias = b_ih + b_hh
// ---------------------------------------------------------------------------
__global__ __launch_bounds__(256) void prep_whh(const float* __restrict__ Whh,
                                                const float* __restrict__ bih,
                                                const float* __restrict__ bhh,
                                                uint4* __restrict__ Wp,
                                                float* __restrict__ bias) {
    int n = blockIdx.x * 256 + threadIdx.x;  // 0..32767
    if (n < 1024) bias[n] = bih[n] + bhh[n];
    int row = n & 1023;
    int k8 = n >> 10;
    union { uint4 u; _Float16 h[8]; } cv;
#pragma unroll
    for (int j = 0; j < 8; ++j) cv.h[j] = (_Float16)Whh[row * 256 + k8 * 8 + j];
    Wp[k8 * 1024 + row] = cv.u;
}

// f32 -> f16, 4 elements/thread
__global__ __launch_bounds__(256) void cvt_f16(const float* __restrict__ in,
                                               _Float16* __restrict__ out, int n4) {
    int i = blockIdx.x * 256 + threadIdx.x;
    if (i < n4) {
        float4 v = ((const float4*)in)[i];
        union { ushort4 u; _Float16 h[4]; } cv;
        cv.h[0] = (_Float16)v.x; cv.h[1] = (_Float16)v.y;
        cv.h[2] = (_Float16)v.z; cv.h[3] = (_Float16)v.w;
        ((ushort4*)out)[i] = cv.u;
    }
}

// ---------------------------------------------------------------------------
// gemm_mfma: C[M][1024] = A[M][K](f16) * W[1024][K](f16)^T + bias, fp32 out.
// ---------------------------------------------------------------------------
__global__ __launch_bounds__(256) void gemm_mfma(const _Float16* __restrict__ A,
                                                 const _Float16* __restrict__ Bw,
                                                 const float* __restrict__ bias,
                                                 float* __restrict__ Cmat, int K) {
    __shared__ _Float16 As[64][72];
    __shared__ _Float16 Bs[64][72];
    const int tid = threadIdx.x;
    const int wave = tid >> 6, lane = tid & 63;
    const int quad = lane >> 4, l16 = lane & 15;
    const int m0 = blockIdx.x * 64, n0 = blockIdx.y * 64;
    const int sr = tid >> 2;
    const int sc = (tid & 3) * 16;

    f32x4 acc[4] = {};

    for (int k0 = 0; k0 < K; k0 += 64) {
        const uint4 a0v = *(const uint4*)(A + (size_t)(m0 + sr) * K + k0 + sc);
        const uint4 a1v = *(const uint4*)(A + (size_t)(m0 + sr) * K + k0 + sc + 8);
        const uint4 b0v = *(const uint4*)(Bw + (size_t)(n0 + sr) * K + k0 + sc);
        const uint4 b1v = *(const uint4*)(Bw + (size_t)(n0 + sr) * K + k0 + sc + 8);
        __syncthreads();
        *(uint4*)&As[sr][sc] = a0v;
        *(uint4*)&As[sr][sc + 8] = a1v;
        *(uint4*)&Bs[sr][sc] = b0v;
        *(uint4*)&Bs[sr][sc + 8] = b1v;
        __syncthreads();
#pragma unroll
        for (int kc = 0; kc < 64; kc += 32) {
            half8_t af = *(const half8_t*)&As[wave * 16 + l16][kc + quad * 8];
#pragma unroll
            for (int nb = 0; nb < 4; ++nb) {
                half8_t bf = *(const half8_t*)&Bs[nb * 16 + l16][kc + quad * 8];
                acc[nb] = __builtin_amdgcn_mfma_f32_16x16x32_f16(af, bf, acc[nb], 0, 0, 0);
            }
        }
    }
#pragma unroll
    for (int nb = 0; nb < 4; ++nb) {
#pragma unroll
        for (int i = 0; i < 4; ++i) {
            int row = m0 + wave * 16 + quad * 4 + i;
            int col = n0 + nb * 16 + l16;
            Cmat[(size_t)row * 1024 + col] = acc[nb][i] + bias[col];
        }
    }
}

// ---------------------------------------------------------------------------
// lstm_scan v5: identical structure to v4, but occupancy pinned with
// amdgpu_waves_per_eu(2,2): exactly 2 waves/SIMD -> VGPR budget 512/2 = 256.
// (__launch_bounds__ 2nd arg is only a LOWER bound on waves/EU; in R3/R4 the
// allocator still chose 4 waves/EU -> 128-VGPR cap -> everything spilled to
// scratch, visible as VGPR_Count=128 + a 40 ms first-touch outlier.)
// Weight placement per thread (rows tid, tid+512):
//   k8 = 0..15  : 128 VGPRs (persistent across all 512 steps)
//   k8 = 16..23 : 128 KB LDS (staged once)
//   k8 = 24..31 : L2, full load at step top (64 VGPR), consumed ~600 cyc later
// ---------------------------------------------------------------------------
__global__ __attribute__((amdgpu_flat_work_group_size(512, 512),
                          amdgpu_waves_per_eu(2, 2)))
void lstm_scan(const float* __restrict__ gx,
               const uint4* __restrict__ Wp,
               _Float16* __restrict__ h_out,
               int store_all) {
    const int b = blockIdx.x;
    const int tid = threadIdx.x;   // 0..511
    const int j = tid & 255;
    const bool isIG = tid < 256;

    __shared__ uint4 wlds[8 * 1024];  // 128 KB: k8 = 16..23, [k8'][row]
    __shared__ _Float16 hsh[256] __attribute__((aligned(16)));
    __shared__ float exf[256];
    __shared__ float exo[256];
    __shared__ _Float16 hist[16][256] __attribute__((aligned(16)));

    // stage k8=16..23 into LDS (flat layout identical to Wp slice)
#pragma unroll
    for (int q = 0; q < 16; ++q) {
        int idx = q * 512 + tid;
        wlds[idx] = Wp[16 * 1024 + idx];
    }

    // persistent register weights: k8 = 0..15, rows tid and tid+512
    uint4 wl[16], wh[16];
#pragma unroll
    for (int u = 0; u < 16; ++u) {
        wl[u] = Wp[u * 1024 + tid];
        wh[u] = Wp[u * 1024 + 512 + tid];
    }
    const uint4* S = Wp + 24 * 1024;  // k8 = 24..31 streamed from L2

    if (isIG) hsh[j] = (_Float16)0.f;
    float c = 0.f;
    const float* gxb = gx + (size_t)b * 512 * 1024;
    float gl = gxb[tid], gh = gxb[512 + tid];  // gx for t=0
    __syncthreads();  // wlds + hsh visible

    for (int t = 0; t < 512; ++t) {
        // issue this step's L2 stream loads; consumed at k8=24..31
        uint4 sl[8], sh[8];
#pragma unroll
        for (int u = 0; u < 8; ++u) {
            sl[u] = S[u * 1024 + tid];
            sh[u] = S[u * 1024 + 512 + tid];
        }
        // prefetch next step's gx
        float gl_n = 0.f, gh_n = 0.f;
        if (t < 511) {
            const float* g4 = gxb + (size_t)(t + 1) * 1024;
            gl_n = g4[tid];
            gh_n = g4[512 + tid];
        }

        const uint4* hb = (const uint4*)hsh;
        float a0x = 0.f, a0y = 0.f, a1x = 0.f, a1y = 0.f;  // split dep chains

        // register half: k8 = 0..15
#pragma unroll
        for (int u = 0; u < 16; ++u) {
            const uint4 hv = hb[u];
            const half2_t h0 = h2(hv.x), h1 = h2(hv.y), hv2 = h2(hv.z), h3 = h2(hv.w);
            a0x = fdot2(h2(wl[u].x), h0, a0x); a0x = fdot2(h2(wl[u].y), h1, a0x);
            a0y = fdot2(h2(wl[u].z), hv2, a0y); a0y = fdot2(h2(wl[u].w), h3, a0y);
            a1x = fdot2(h2(wh[u].x), h0, a1x); a1x = fdot2(h2(wh[u].y), h1, a1x);
            a1y = fdot2(h2(wh[u].z), hv2, a1y); a1y = fdot2(h2(wh[u].w), h3, a1y);
        }
        // LDS half: k8 = 16..23
#pragma unroll
        for (int u = 0; u < 8; ++u) {
            const uint4 cl = wlds[u * 1024 + tid];
            const uint4 ch = wlds[u * 1024 + 512 + tid];
            const uint4 hv = hb[16 + u];
            const half2_t h0 = h2(hv.x), h1 = h2(hv.y), hv2 = h2(hv.z), h3 = h2(hv.w);
            a0x = fdot2(h2(cl.x), h0, a0x); a0x = fdot2(h2(cl.y), h1, a0x);
            a0y = fdot2(h2(cl.z), hv2, a0y); a0y = fdot2(h2(cl.w), h3, a0y);
            a1x = fdot2(h2(ch.x), h0, a1x); a1x = fdot2(h2(ch.y), h1, a1x);
            a1y = fdot2(h2(ch.z), hv2, a1y); a1y = fdot2(h2(ch.w), h3, a1y);
        }
        // streamed half: k8 = 24..31 (loads issued at step top)
#pragma unroll
        for (int u = 0; u < 8; ++u) {
            const uint4 cl = sl[u], ch = sh[u];
            const uint4 hv = hb[24 + u];
            const half2_t h0 = h2(hv.x), h1 = h2(hv.y), hv2 = h2(hv.z), h3 = h2(hv.w);
            a0x = fdot2(h2(cl.x), h0, a0x); a0x = fdot2(h2(cl.y), h1, a0x);
            a0y = fdot2(h2(cl.z), hv2, a0y); a0y = fdot2(h2(cl.w), h3, a0y);
            a1x = fdot2(h2(ch.x), h0, a1x); a1x = fdot2(h2(ch.y), h1, a1x);
            a1y = fdot2(h2(ch.z), hv2, a1y); a1y = fdot2(h2(ch.w), h3, a1y);
        }

        const float plo = a0x + a0y + gl;  // pre-activation, row tid
        const float phi = a1x + a1y + gh;  // pre-activation, row tid+512
        float v0 = 0.f, v1 = 0.f;
        if (isIG) {
            v0 = sigm(plo);        // i_j
            v1 = tanh_fast(phi);   // g_j
        } else {
            exf[j] = sigm(plo);    // f_j
            exo[j] = sigm(phi);    // o_j
        }
        gl = gl_n; gh = gh_n;
        __syncthreads();           // exchange visible; all hsh reads done
        if (isIG) {
            const float fv = exf[j], ov = exo[j];
            c = fv * c + v0 * v1;
            const _Float16 hh = (_Float16)(ov * tanh_fast(c));
            hsh[j] = hh;
            hist[t & 15][j] = hh;
        }
        __syncthreads();           // new h visible
        if (store_all && (t & 15) == 15) {
            const uint4 v = ((const uint4*)hist)[tid];
            *(uint4*)(h_out + (size_t)b * 512 * 256 + (size_t)(t - 15) * 256 + tid * 8) = v;
        }
    }
    if (!store_all && isIG) {
        h_out[(size_t)b * 256 + j] = hsh[j];  // compact last-h for the FC
    }
}

// ---------------------------------------------------------------------------
// fc_softmax: logits = hlast[b,:](f16) @ fc_w^T + fc_b, softmax over 3
// ---------------------------------------------------------------------------
__global__ __launch_bounds__(64) void fc_softmax(const _Float16* __restrict__ hlast,
                                                 const float* __restrict__ fcw,
                                                 const float* __restrict__ fcb,
                                                 float* __restrict__ out) {
    const int b = blockIdx.x;
    const int lane = threadIdx.x;
    const _Float16* h = hlast + (size_t)b * 256;
    float p0 = 0.f, p1 = 0.f, p2 = 0.f;
    for (int k = lane; k < 256; k += 64) {
        float hv = (float)h[k];
        p0 += hv * fcw[k];
        p1 += hv * fcw[256 + k];
        p2 += hv * fcw[512 + k];
    }
#pragma unroll
    for (int off = 32; off > 0; off >>= 1) {
        p0 += __shfl_down(p0, off);
        p1 += __shfl_down(p1, off);
        p2 += __shfl_down(p2, off);
    }
    if (lane == 0) {
        float l0 = p0 + fcb[0], l1 = p1 + fcb[1], l2 = p2 + fcb[2];
        float m = fmaxf(l0, fmaxf(l1, l2));
        float e0 = __expf(l0 - m), e1 = __expf(l1 - m), e2 = __expf(l2 - m);
        float s = 1.f / (e0 + e1 + e2);
        out[b * 3 + 0] = e0 * s;
        out[b * 3 + 1] = e1 * s;
        out[b * 3 + 2] = e2 * s;
    }
}

extern "C" void kernel_launch(void* const* d_in, const int* in_sizes, int n_in,
                              void* d_out, int out_size, void* d_ws, size_t ws_size,
                              hipStream_t stream) {
    const float* x    = (const float*)d_in[0];
    const float* Wih0 = (const float*)d_in[1];
    const float* Whh0 = (const float*)d_in[2];
    const float* bih0 = (const float*)d_in[3];
    const float* bhh0 = (const float*)d_in[4];
    const float* Wih1 = (const float*)d_in[5];
    const float* Whh1 = (const float*)d_in[6];
    const float* bih1 = (const float*)d_in[7];
    const float* bhh1 = (const float*)d_in[8];
    const float* fcw  = (const float*)d_in[9];
    const float* fcb  = (const float*)d_in[10];
    float* out = (float*)d_out;

    // workspace layout (~161 MB)
    char* ws = (char*)d_ws;
    float* gx        = (float*)ws;     ws += (size_t)32768 * 1024 * 4;  // 134.2 MB
    _Float16* h0f    = (_Float16*)ws;  ws += (size_t)32768 * 256 * 2;   // 16.8 MB
    _Float16* xh     = (_Float16*)ws;  ws += (size_t)32768 * 128 * 2;   // 8.4 MB
    _Float16* hlast  = (_Float16*)ws;  ws += (size_t)64 * 256 * 2;      // 32 KB
    _Float16* Wih0h  = (_Float16*)ws;  ws += (size_t)1024 * 128 * 2;    // 256 KB
    _Float16* Wih1h  = (_Float16*)ws;  ws += (size_t)1024 * 256 * 2;    // 512 KB
    uint4* Wp0       = (uint4*)ws;     ws += (size_t)1024 * 256 * 2;    // 512 KB
    uint4* Wp1       = (uint4*)ws;     ws += (size_t)1024 * 256 * 2;    // 512 KB
    float* bias0     = (float*)ws;     ws += 4096;
    float* bias1     = (float*)ws;     ws += 4096;

    prep_whh<<<128, 256, 0, stream>>>(Whh0, bih0, bhh0, Wp0, bias0);
    prep_whh<<<128, 256, 0, stream>>>(Whh1, bih1, bhh1, Wp1, bias1);
    cvt_f16<<<4096, 256, 0, stream>>>(x, xh, 32768 * 128 / 4);
    cvt_f16<<<128, 256, 0, stream>>>(Wih0, Wih0h, 1024 * 128 / 4);
    cvt_f16<<<256, 256, 0, stream>>>(Wih1, Wih1h, 1024 * 256 / 4);

    // layer 0
    gemm_mfma<<<dim3(512, 16), 256, 0, stream>>>(xh, Wih0h, bias0, gx, 128);
    lstm_scan<<<64, 512, 0, stream>>>(gx, Wp0, h0f, 1);

    // layer 1
    gemm_mfma<<<dim3(512, 16), 256, 0, stream>>>(h0f, Wih1h, bias1, gx, 256);
    lstm_scan<<<64, 512, 0, stream>>>(gx, Wp1, hlast, 0);

    fc_softmax<<<64, 64, 0, stream>>>(hlast, fcw, fcb, out);
}

// Round 6
// 2136.783 us; speedup vs baseline: 2.2079x; 1.0564x over previous
//
#include <hip/hip_runtime.h>
#include <cstdint>
#include <cstddef>

// Problem: B=64, T=512, I=128, H=256, 4H=1024, C=3. All fp32 in/out.
typedef _Float16 half2_t __attribute__((ext_vector_type(2)));
typedef _Float16 half8_t __attribute__((ext_vector_type(8)));
typedef float f32x4 __attribute__((ext_vector_type(4)));

static __device__ __forceinline__ float fdot2(half2_t a, half2_t b, float c) {
    return __builtin_amdgcn_fdot2(a, b, c, false);
}
static __device__ __forceinline__ half2_t h2(unsigned int u) {
    return __builtin_bit_cast(half2_t, u);
}
static __device__ __forceinline__ float sigm(float x) {
    return 1.f / (1.f + __expf(-x));
}
static __device__ __forceinline__ float tanh_fast(float x) {
    float ax = fabsf(x);
    float e = __expf(2.f * ax);
    float r = 1.f - 2.f / (e + 1.f);
    return copysignf(r, x);
}

// ---------------------------------------------------------------------------
// prep: W_hh (1024x256 fp32) -> f16 k8-major: Wp[k8*1024 + row] = 8 halves of
// W[row][8*k8..]; bias = b_ih + b_hh
// ---------------------------------------------------------------------------
__global__ __launch_bounds__(256) void prep_whh(const float* __restrict__ Whh,
                                                const float* __restrict__ bih,
                                                const float* __restrict__ bhh,
                                                uint4* __restrict__ Wp,
                                                float* __restrict__ bias) {
    int n = blockIdx.x * 256 + threadIdx.x;  // 0..32767
    if (n < 1024) bias[n] = bih[n] + bhh[n];
    int row = n & 1023;
    int k8 = n >> 10;
    union { uint4 u; _Float16 h[8]; } cv;
#pragma unroll
    for (int j = 0; j < 8; ++j) cv.h[j] = (_Float16)Whh[row * 256 + k8 * 8 + j];
    Wp[k8 * 1024 + row] = cv.u;
}

// f32 -> f16, 4 elements/thread
__global__ __launch_bounds__(256) void cvt_f16(const float* __restrict__ in,
                                               _Float16* __restrict__ out, int n4) {
    int i = blockIdx.x * 256 + threadIdx.x;
    if (i < n4) {
        float4 v = ((const float4*)in)[i];
        union { ushort4 u; _Float16 h[4]; } cv;
        cv.h[0] = (_Float16)v.x; cv.h[1] = (_Float16)v.y;
        cv.h[2] = (_Float16)v.z; cv.h[3] = (_Float16)v.w;
        ((ushort4*)out)[i] = cv.u;
    }
}

// ---------------------------------------------------------------------------
// gemm_mfma: C[M][1024] = A[M][K](f16) * W[1024][K](f16)^T + bias, fp32 out.
// ---------------------------------------------------------------------------
__global__ __launch_bounds__(256) void gemm_mfma(const _Float16* __restrict__ A,
                                                 const _Float16* __restrict__ Bw,
                                                 const float* __restrict__ bias,
                                                 float* __restrict__ Cmat, int K) {
    __shared__ _Float16 As[64][72];
    __shared__ _Float16 Bs[64][72];
    const int tid = threadIdx.x;
    const int wave = tid >> 6, lane = tid & 63;
    const int quad = lane >> 4, l16 = lane & 15;
    const int m0 = blockIdx.x * 64, n0 = blockIdx.y * 64;
    const int sr = tid >> 2;
    const int sc = (tid & 3) * 16;

    f32x4 acc[4] = {};

    for (int k0 = 0; k0 < K; k0 += 64) {
        const uint4 a0v = *(const uint4*)(A + (size_t)(m0 + sr) * K + k0 + sc);
        const uint4 a1v = *(const uint4*)(A + (size_t)(m0 + sr) * K + k0 + sc + 8);
        const uint4 b0v = *(const uint4*)(Bw + (size_t)(n0 + sr) * K + k0 + sc);
        const uint4 b1v = *(const uint4*)(Bw + (size_t)(n0 + sr) * K + k0 + sc + 8);
        __syncthreads();
        *(uint4*)&As[sr][sc] = a0v;
        *(uint4*)&As[sr][sc + 8] = a1v;
        *(uint4*)&Bs[sr][sc] = b0v;
        *(uint4*)&Bs[sr][sc + 8] = b1v;
        __syncthreads();
#pragma unroll
        for (int kc = 0; kc < 64; kc += 32) {
            half8_t af = *(const half8_t*)&As[wave * 16 + l16][kc + quad * 8];
#pragma unroll
            for (int nb = 0; nb < 4; ++nb) {
                half8_t bf = *(const half8_t*)&Bs[nb * 16 + l16][kc + quad * 8];
                acc[nb] = __builtin_amdgcn_mfma_f32_16x16x32_f16(af, bf, acc[nb], 0, 0, 0);
            }
        }
    }
#pragma unroll
    for (int nb = 0; nb < 4; ++nb) {
#pragma unroll
        for (int i = 0; i < 4; ++i) {
            int row = m0 + wave * 16 + quad * 4 + i;
            int col = n0 + nb * 16 + l16;
            Cmat[(size_t)row * 1024 + col] = acc[nb][i] + bias[col];
        }
    }
}

// ---------------------------------------------------------------------------
// lstm_scan v6: 64 WGs x 1024 thr (16 waves = 4 waves/SIMD at the 128-VGPR
// allocator operating point; amdgpu_flat_work_group_size(1024,1024) makes
// 128 a HARD cap, aligning compiler constraint with design).
// Thread tid owns ONE gate row (tid): 128 fdot2/step.
//   k8 = 0..23  : 24 uint4 = 96 VGPRs, persistent all 512 steps
//   k8 = 24..31 : 128 KB LDS, staged once
// -> zero per-step L2 weight traffic; per step a WG reads only 4 KB gx.
// Gates exchanged via 4 KB LDS; threads 0..255 update c,h. 2 barriers/step.
// ---------------------------------------------------------------------------
__global__ __attribute__((amdgpu_flat_work_group_size(1024, 1024)))
void lstm_scan(const float* __restrict__ gx,
               const uint4* __restrict__ Wp,
               _Float16* __restrict__ h_out,
               int store_all) {
    const int b = blockIdx.x;
    const int tid = threadIdx.x;   // 0..1023 = gate row
    const int j = tid & 255;       // hidden unit
    const int gsel = tid >> 8;     // 0=i 1=f 2=g 3=o

    __shared__ uint4 wlds[8 * 1024];  // 128 KB: k8 = 24..31, [k8'][row]
    __shared__ _Float16 hsh[256] __attribute__((aligned(16)));
    __shared__ float actf[1024];
    __shared__ _Float16 hist[16][256] __attribute__((aligned(16)));

    // stage k8=24..31 into LDS
#pragma unroll
    for (int q = 0; q < 8; ++q) {
        wlds[q * 1024 + tid] = Wp[(24 + q) * 1024 + tid];
    }
    // persistent register weights: k8 = 0..23 (96 VGPRs)
    uint4 wreg[24];
#pragma unroll
    for (int u = 0; u < 24; ++u) wreg[u] = Wp[u * 1024 + tid];

    if (tid < 256) hsh[j] = (_Float16)0.f;
    float c = 0.f;
    const float* gxb = gx + (size_t)b * 512 * 1024;
    float g_cur = gxb[tid];  // gx for t=0
    __syncthreads();  // wlds + hsh visible

    for (int t = 0; t < 512; ++t) {
        // prefetch next step's gx (consumed next iteration)
        float g_nxt = 0.f;
        if (t < 511) g_nxt = gxb[(size_t)(t + 1) * 1024 + tid];

        const uint4* hb = (const uint4*)hsh;
        float ax = 0.f, ay = 0.f;  // split dep chains

        // register part: k8 = 0..23
#pragma unroll
        for (int u = 0; u < 24; ++u) {
            const uint4 hv = hb[u];
            ax = fdot2(h2(wreg[u].x), h2(hv.x), ax);
            ax = fdot2(h2(wreg[u].y), h2(hv.y), ax);
            ay = fdot2(h2(wreg[u].z), h2(hv.z), ay);
            ay = fdot2(h2(wreg[u].w), h2(hv.w), ay);
        }
        // LDS part: k8 = 24..31
#pragma unroll
        for (int u = 0; u < 8; ++u) {
            const uint4 wv = wlds[u * 1024 + tid];
            const uint4 hv = hb[24 + u];
            ax = fdot2(h2(wv.x), h2(hv.x), ax);
            ax = fdot2(h2(wv.y), h2(hv.y), ax);
            ay = fdot2(h2(wv.z), h2(hv.z), ay);
            ay = fdot2(h2(wv.w), h2(hv.w), ay);
        }

        const float a = ax + ay + g_cur;
        actf[tid] = (gsel == 2) ? tanh_fast(a) : sigm(a);
        g_cur = g_nxt;
        __syncthreads();           // act visible; all hsh reads done

        if (tid < 256) {
            const float iv = actf[j], fv = actf[256 + j];
            const float gv = actf[512 + j], ov = actf[768 + j];
            c = fv * c + iv * gv;
            const _Float16 hh = (_Float16)(ov * tanh_fast(c));
            hsh[j] = hh;
            if (store_all) hist[t & 15][j] = hh;
        }
        __syncthreads();           // new h visible

        if (store_all && (t & 15) == 15) {
            // flush 16 steps (8 KB) with all 1024 threads (8 B each)
            const uint2 v = ((const uint2*)hist)[tid];
            *(uint2*)(h_out + (size_t)b * 512 * 256 + (size_t)(t - 15) * 256 + tid * 4) = v;
        }
    }
    if (!store_all && tid < 256) {
        h_out[(size_t)b * 256 + j] = hsh[j];  // compact last-h for the FC
    }
}

// ---------------------------------------------------------------------------
// fc_softmax: logits = hlast[b,:](f16) @ fc_w^T + fc_b, softmax over 3
// ---------------------------------------------------------------------------
__global__ __launch_bounds__(64) void fc_softmax(const _Float16* __restrict__ hlast,
                                                 const float* __restrict__ fcw,
                                                 const float* __restrict__ fcb,
                                                 float* __restrict__ out) {
    const int b = blockIdx.x;
    const int lane = threadIdx.x;
    const _Float16* h = hlast + (size_t)b * 256;
    float p0 = 0.f, p1 = 0.f, p2 = 0.f;
    for (int k = lane; k < 256; k += 64) {
        float hv = (float)h[k];
        p0 += hv * fcw[k];
        p1 += hv * fcw[256 + k];
        p2 += hv * fcw[512 + k];
    }
#pragma unroll
    for (int off = 32; off > 0; off >>= 1) {
        p0 += __shfl_down(p0, off);
        p1 += __shfl_down(p1, off);
        p2 += __shfl_down(p2, off);
    }
    if (lane == 0) {
        float l0 = p0 + fcb[0], l1 = p1 + fcb[1], l2 = p2 + fcb[2];
        float m = fmaxf(l0, fmaxf(l1, l2));
        float e0 = __expf(l0 - m), e1 = __expf(l1 - m), e2 = __expf(l2 - m);
        float s = 1.f / (e0 + e1 + e2);
        out[b * 3 + 0] = e0 * s;
        out[b * 3 + 1] = e1 * s;
        out[b * 3 + 2] = e2 * s;
    }
}

extern "C" void kernel_launch(void* const* d_in, const int* in_sizes, int n_in,
                              void* d_out, int out_size, void* d_ws, size_t ws_size,
                              hipStream_t stream) {
    const float* x    = (const float*)d_in[0];
    const float* Wih0 = (const float*)d_in[1];
    const float* Whh0 = (const float*)d_in[2];
    const float* bih0 = (const float*)d_in[3];
    const float* bhh0 = (const float*)d_in[4];
    const float* Wih1 = (const float*)d_in[5];
    const float* Whh1 = (const float*)d_in[6];
    const float* bih1 = (const float*)d_in[7];
    const float* bhh1 = (const float*)d_in[8];
    const float* fcw  = (const float*)d_in[9];
    const float* fcb  = (const float*)d_in[10];
    float* out = (float*)d_out;

    // workspace layout (~161 MB)
    char* ws = (char*)d_ws;
    float* gx        = (float*)ws;     ws += (size_t)32768 * 1024 * 4;  // 134.2 MB
    _Float16* h0f    = (_Float16*)ws;  ws += (size_t)32768 * 256 * 2;   // 16.8 MB
    _Float16* xh     = (_Float16*)ws;  ws += (size_t)32768 * 128 * 2;   // 8.4 MB
    _Float16* hlast  = (_Float16*)ws;  ws += (size_t)64 * 256 * 2;      // 32 KB
    _Float16* Wih0h  = (_Float16*)ws;  ws += (size_t)1024 * 128 * 2;    // 256 KB
    _Float16* Wih1h  = (_Float16*)ws;  ws += (size_t)1024 * 256 * 2;    // 512 KB
    uint4* Wp0       = (uint4*)ws;     ws += (size_t)1024 * 256 * 2;    // 512 KB
    uint4* Wp1       = (uint4*)ws;     ws += (size_t)1024 * 256 * 2;    // 512 KB
    float* bias0     = (float*)ws;     ws += 4096;
    float* bias1     = (float*)ws;     ws += 4096;

    prep_whh<<<128, 256, 0, stream>>>(Whh0, bih0, bhh0, Wp0, bias0);
    prep_whh<<<128, 256, 0, stream>>>(Whh1, bih1, bhh1, Wp1, bias1);
    cvt_f16<<<4096, 256, 0, stream>>>(x, xh, 32768 * 128 / 4);
    cvt_f16<<<128, 256, 0, stream>>>(Wih0, Wih0h, 1024 * 128 / 4);
    cvt_f16<<<256, 256, 0, stream>>>(Wih1, Wih1h, 1024 * 256 / 4);

    // layer 0
    gemm_mfma<<<dim3(512, 16), 256, 0, stream>>>(xh, Wih0h, bias0, gx, 128);
    lstm_scan<<<64, 1024, 0, stream>>>(gx, Wp0, h0f, 1);

    // layer 1
    gemm_mfma<<<dim3(512, 16), 256, 0, stream>>>(h0f, Wih1h, bias1, gx, 256);
    lstm_scan<<<64, 1024, 0, stream>>>(gx, Wp1, hlast, 0);

    fc_softmax<<<64, 64, 0, stream>>>(hlast, fcw, fcb, out);
}